// Round 6
// baseline (260.195 us; speedup 1.0000x reference)
//
#include <hip/hip_runtime.h>
#include <math.h>

#define N_NODES 32768
#define NPG 512
#define NGRAPH 64
#define KKEEP 256
#define CAP 64

typedef __attribute__((ext_vector_type(8))) short short8;
typedef __attribute__((ext_vector_type(4))) float f32x4;

__device__ __forceinline__ unsigned short f2bf(float v) {
  unsigned u = __builtin_bit_cast(unsigned, v);
  u = (u + 0x7FFFu + ((u >> 16) & 1u)) >> 16;
  return (unsigned short)u;
}
__device__ __forceinline__ float bf2f(unsigned short u) {
  unsigned v = ((unsigned)u) << 16;
  return __builtin_bit_cast(float, v);
}

// ---- merged: edge bucketing (blocks 0..2047) + x/W split-bf16 convert ----
__global__ __launch_bounds__(256) void k_hist_conv(
    const int* __restrict__ ei, int E, int* __restrict__ cnt,
    unsigned short* __restrict__ nbr,
    const float* __restrict__ x, const float* __restrict__ W,
    unsigned short* __restrict__ xh, unsigned short* __restrict__ xl,
    unsigned short* __restrict__ wth, unsigned short* __restrict__ wtl,
    unsigned short* __restrict__ wtll) {
  const int t = threadIdx.x;
  if (blockIdx.x < 2048) {
    int e = blockIdx.x * 256 + t;
    if (e < E) {
      int s = ei[e];
      int d = ei[E + e];
      int slot = atomicAdd(&cnt[d], 1);
      if (slot < CAP) nbr[(size_t)d * CAP + slot] = (unsigned short)(s & (NPG - 1));
    }
  } else if (blockIdx.x < 4096) {
    size_t base = ((size_t)(blockIdx.x - 2048) * 256 + t) * 16;
    unsigned short hb[16], lb[16];
#pragma unroll
    for (int g = 0; g < 4; g++) {
      float4 v = *(const float4*)&x[base + g * 4];
      float f[4] = {v.x, v.y, v.z, v.w};
#pragma unroll
      for (int j = 0; j < 4; j++) {
        unsigned short hh = f2bf(f[j]);
        float e1 = f[j] - bf2f(hh);          // exact
        hb[g * 4 + j] = hh;
        lb[g * 4 + j] = f2bf(e1);
      }
    }
    *(uint4*)&xh[base] = *(uint4*)&hb[0];
    *(uint4*)&xh[base + 8] = *(uint4*)&hb[8];
    *(uint4*)&xl[base] = *(uint4*)&lb[0];
    *(uint4*)&xl[base + 8] = *(uint4*)&lb[8];
  } else {
    int bw = blockIdx.x - 4096;              // 0..63
    int n = bw * 4 + (t >> 6);               // output col of W
    int k = (t & 63) * 4;
    unsigned short hb[4], lb[4], qb[4];
#pragma unroll
    for (int j = 0; j < 4; j++) {
      float v = W[(size_t)(k + j) * 256 + n];
      unsigned short hh = f2bf(v);
      float e1 = v - bf2f(hh);               // exact
      unsigned short ll = f2bf(e1);
      float e2 = e1 - bf2f(ll);              // exact
      hb[j] = hh; lb[j] = ll; qb[j] = f2bf(e2);
    }
    *(uint2*)&wth[(size_t)n * 256 + k] = *(uint2*)&hb[0];
    *(uint2*)&wtl[(size_t)n * 256 + k] = *(uint2*)&lb[0];
    *(uint2*)&wtll[(size_t)n * 256 + k] = *(uint2*)&qb[0];
  }
}

// ---- MFMA split-3 bf16 GEMM: h = x@W (+fused a_src/a_dst) ----
__global__ __launch_bounds__(256) void k_gemm(
    const float* __restrict__ x,
    const unsigned short* __restrict__ xhp, const unsigned short* __restrict__ xlp,
    const unsigned short* __restrict__ wth, const unsigned short* __restrict__ wtl,
    const unsigned short* __restrict__ wtll,
    const float* __restrict__ attS, const float* __restrict__ attD,
    float* __restrict__ h, float* __restrict__ a_src, float* __restrict__ a_dst) {
  __shared__ unsigned short As[3][128][40];
  __shared__ unsigned short Bs[3][128][40];
  const int t = threadIdx.x;
  const int mb = blockIdx.x >> 1, nh = blockIdx.x & 1;
  const int row0 = mb * 128;
  const int wid = t >> 6, lane = t & 63;
  const int q = lane >> 4, ln = lane & 15;
  const int wm = (wid >> 1) * 64, wn = (wid & 1) * 64;
  f32x4 acc[4][4] = {};

  for (int kc = 0; kc < 8; kc++) {
    const int k0 = kc * 32;
#pragma unroll
    for (int i = 0; i < 2; i++) {
      int c = i * 256 + t;
      int r = c >> 2, ko = (c & 3) * 8;
      size_t ga = (size_t)(row0 + r) * 256 + k0 + ko;
      uint4 vh = *(const uint4*)&xhp[ga];
      uint4 vl = *(const uint4*)&xlp[ga];
      *(uint4*)&As[0][r][ko] = vh;
      *(uint4*)&As[1][r][ko] = vl;
      float4 f0 = *(const float4*)&x[ga];
      float4 f1 = *(const float4*)&x[ga + 4];
      unsigned short hs[8], ls[8], qs[8];
      *(uint4*)&hs[0] = vh;
      *(uint4*)&ls[0] = vl;
      float ff[8] = {f0.x, f0.y, f0.z, f0.w, f1.x, f1.y, f1.z, f1.w};
#pragma unroll
      for (int j = 0; j < 8; j++)
        qs[j] = f2bf(ff[j] - bf2f(hs[j]) - bf2f(ls[j]));   // exact residual
      *(uint4*)&As[2][r][ko] = *(uint4*)&qs[0];
      size_t gb = (size_t)(nh * 128 + r) * 256 + k0 + ko;
      *(uint4*)&Bs[0][r][ko] = *(const uint4*)&wth[gb];
      *(uint4*)&Bs[1][r][ko] = *(const uint4*)&wtl[gb];
      *(uint4*)&Bs[2][r][ko] = *(const uint4*)&wtll[gb];
    }
    __syncthreads();
    short8 ah[4], al[4], aq[4];
#pragma unroll
    for (int mt = 0; mt < 4; mt++) {
      ah[mt] = *(const short8*)&As[0][wm + mt * 16 + ln][q * 8];
      al[mt] = *(const short8*)&As[1][wm + mt * 16 + ln][q * 8];
      aq[mt] = *(const short8*)&As[2][wm + mt * 16 + ln][q * 8];
    }
#pragma unroll
    for (int nt = 0; nt < 4; nt++) {
      short8 bh = *(const short8*)&Bs[0][wn + nt * 16 + ln][q * 8];
      short8 bl = *(const short8*)&Bs[1][wn + nt * 16 + ln][q * 8];
      short8 bq = *(const short8*)&Bs[2][wn + nt * 16 + ln][q * 8];
#pragma unroll
      for (int mt = 0; mt < 4; mt++) {
        acc[mt][nt] = __builtin_amdgcn_mfma_f32_16x16x32_bf16(ah[mt], bh, acc[mt][nt], 0, 0, 0);
        acc[mt][nt] = __builtin_amdgcn_mfma_f32_16x16x32_bf16(ah[mt], bl, acc[mt][nt], 0, 0, 0);
        acc[mt][nt] = __builtin_amdgcn_mfma_f32_16x16x32_bf16(al[mt], bh, acc[mt][nt], 0, 0, 0);
        acc[mt][nt] = __builtin_amdgcn_mfma_f32_16x16x32_bf16(ah[mt], bq, acc[mt][nt], 0, 0, 0);
        acc[mt][nt] = __builtin_amdgcn_mfma_f32_16x16x32_bf16(al[mt], bl, acc[mt][nt], 0, 0, 0);
        acc[mt][nt] = __builtin_amdgcn_mfma_f32_16x16x32_bf16(aq[mt], bh, acc[mt][nt], 0, 0, 0);
      }
    }
    __syncthreads();
  }
  const int head = nh * 2 + (wid & 1);
  float sA[4], sD[4];
#pragma unroll
  for (int nt = 0; nt < 4; nt++) {
    int n = nh * 128 + wn + nt * 16 + ln;
    sA[nt] = attS[n];
    sD[nt] = attD[n];
  }
#pragma unroll
  for (int mt = 0; mt < 4; mt++) {
#pragma unroll
    for (int reg = 0; reg < 4; reg++) {
      int m = row0 + wm + mt * 16 + q * 4 + reg;
      float ps = 0.f, pd = 0.f;
#pragma unroll
      for (int nt = 0; nt < 4; nt++) {
        float v = acc[mt][nt][reg];
        h[(size_t)m * 256 + nh * 128 + wn + nt * 16 + ln] = v;
        ps = fmaf(v, sA[nt], ps);
        pd = fmaf(v, sD[nt], pd);
      }
#pragma unroll
      for (int d = 1; d < 16; d <<= 1) {
        ps += __shfl_xor(ps, d, 16);
        pd += __shfl_xor(pd, d, 16);
      }
      if (ln == 0) {
        a_src[m * 4 + head] = ps;
        a_dst[m * 4 + head] = pd;
      }
    }
  }
}

// ---- aggregation: softmax weights computed once, broadcast via LDS ----
__global__ __launch_bounds__(256) void k_agg(
    const float* __restrict__ h, const float* __restrict__ a_src,
    const float* __restrict__ a_dst, const int* __restrict__ cnt,
    const unsigned short* __restrict__ nbr, const float* __restrict__ bias,
    float* __restrict__ feat) {
  __shared__ float p_lds[4][68][4];   // [wave][edge][head], unnormalized
  __shared__ int s_lds[4][68];        // global src index
  const int wv = threadIdx.x >> 6;
  const int lane = threadIdx.x & 63;
  int nb = (blockIdx.x & 7) * (N_NODES / 4 / 8) + (blockIdx.x >> 3);
  const int node = nb * 4 + wv;
  const int head = lane >> 4;
  const int li = lane & 15;
  const int c0 = lane * 4;
  const int base = node & ~(NPG - 1);
  const float ad = a_dst[node * 4 + head];
  int n = cnt[node];
  if (n > CAP) n = CAP;
  // pass 1: lanes in head-group split edges (incl. self at j==n)
  float e_reg[5];
  int srcs[5];
  int nit = 0;
  float m = -1e30f;
  for (int j = li; j <= n; j += 16) {
    int s = (j < n) ? base + (int)nbr[(size_t)node * CAP + j] : node;
    float e = a_src[s * 4 + head] + ad;
    e = (e > 0.f) ? e : 0.2f * e;
    srcs[nit] = s;
    e_reg[nit++] = e;
    m = fmaxf(m, e);
  }
#pragma unroll
  for (int d = 1; d < 16; d <<= 1) m = fmaxf(m, __shfl_xor(m, d, 16));
  float l = 0.f;
  for (int i = 0; i < nit; i++) {
    int j = li + i * 16;
    float p = __expf(e_reg[i] - m);
    l += p;
    p_lds[wv][j][head] = p;
    if (head == 0) s_lds[wv][j] = srcs[i];
  }
#pragma unroll
  for (int d = 1; d < 16; d <<= 1) l += __shfl_xor(l, d, 16);
  const float linv = 1.f / (l + 1e-16f);
  __builtin_amdgcn_s_waitcnt(0);  // drain lgkm before cross-lane LDS reads
  // pass 2: lean weighted sum over n+1 entries
  float4 acc0 = make_float4(0.f, 0.f, 0.f, 0.f);
  float4 acc1 = make_float4(0.f, 0.f, 0.f, 0.f);
  int j = 0;
  for (; j + 1 <= n; j += 2) {
    float p0 = p_lds[wv][j][head];
    float p1 = p_lds[wv][j + 1][head];
    int s0 = s_lds[wv][j];
    int s1 = s_lds[wv][j + 1];
    float4 h0 = *(const float4*)&h[(size_t)s0 * 256 + c0];
    float4 h1 = *(const float4*)&h[(size_t)s1 * 256 + c0];
    acc0.x = fmaf(p0, h0.x, acc0.x); acc1.x = fmaf(p1, h1.x, acc1.x);
    acc0.y = fmaf(p0, h0.y, acc0.y); acc1.y = fmaf(p1, h1.y, acc1.y);
    acc0.z = fmaf(p0, h0.z, acc0.z); acc1.z = fmaf(p1, h1.z, acc1.z);
    acc0.w = fmaf(p0, h0.w, acc0.w); acc1.w = fmaf(p1, h1.w, acc1.w);
  }
  if (j <= n) {
    float p0 = p_lds[wv][j][head];
    int s0 = s_lds[wv][j];
    float4 h0 = *(const float4*)&h[(size_t)s0 * 256 + c0];
    acc0.x = fmaf(p0, h0.x, acc0.x);
    acc0.y = fmaf(p0, h0.y, acc0.y);
    acc0.z = fmaf(p0, h0.z, acc0.z);
    acc0.w = fmaf(p0, h0.w, acc0.w);
  }
  const float4 b4 = *(const float4*)&bias[c0];
  float4 o;
  o.x = fmaxf(fmaf(acc0.x + acc1.x, linv, b4.x), 0.f);
  o.y = fmaxf(fmaf(acc0.y + acc1.y, linv, b4.y), 0.f);
  o.z = fmaxf(fmaf(acc0.z + acc1.z, linv, b4.z), 0.f);
  o.w = fmaxf(fmaf(acc0.w + acc1.w, linv, b4.w), 0.f);
  *(float4*)&feat[(size_t)node * 256 + c0] = o;
}

// ---- BN stats ----
__global__ __launch_bounds__(256) void k_bn_partial(const float* __restrict__ feat,
                                                    double* __restrict__ psum,
                                                    double* __restrict__ psq) {
  const int c = threadIdx.x;
  const int r0 = blockIdx.x * 128;
  double s = 0.0, q = 0.0;
  for (int i = 0; i < 128; i++) {
    double v = (double)feat[(size_t)(r0 + i) * 256 + c];
    s += v;
    q += v * v;
  }
  psum[blockIdx.x * 256 + c] = s;
  psq[blockIdx.x * 256 + c] = q;
}

// cA/cB for output BN; sv[c]=cA*pwn, sv[256]=sum(cB*pwn) for fused score
__global__ __launch_bounds__(1024) void k_bn_final(
    const double* __restrict__ psum, const double* __restrict__ psq,
    const float* __restrict__ gam, const float* __restrict__ bet,
    const float* __restrict__ pw, float* __restrict__ cA, float* __restrict__ cB,
    float* __restrict__ sv) {
  __shared__ double reds[4][256];
  __shared__ double redq[4][256];
  __shared__ double wsq[256];
  __shared__ double sb[256];
  const int t = threadIdx.x;
  const int c = t & 255, sl = t >> 8;
  double s = 0.0, q = 0.0;
  for (int i = sl * 64; i < sl * 64 + 64; i++) {
    s += psum[i * 256 + c];
    q += psq[i * 256 + c];
  }
  reds[sl][c] = s;
  redq[sl][c] = q;
  if (sl == 0) {
    double w = (double)pw[c];
    wsq[c] = w * w;
  }
  __syncthreads();
  if (t == 0) {
    double nn = 0.0;
    for (int i = 0; i < 256; i++) nn += wsq[i];
    wsq[0] = sqrt(nn);
  }
  __syncthreads();
  if (sl == 0) {
    s = reds[0][c] + reds[1][c] + reds[2][c] + reds[3][c];
    q = redq[0][c] + redq[1][c] + redq[2][c] + redq[3][c];
    double mean = s / (double)N_NODES;
    double var = q / (double)N_NODES - mean * mean;
    double a = (double)gam[c] / sqrt(var + 1e-5);
    double cb = (double)bet[c] - mean * a;
    cA[c] = (float)a;
    cB[c] = (float)cb;
    double pwnv = (double)pw[c] / wsq[0];
    sv[c] = (float)(a * pwnv);
    sb[c] = cb * pwnv;
  }
  __syncthreads();
  if (t == 0) {
    double s0 = 0.0;
    for (int i = 0; i < 256; i++) s0 += sb[i];
    sv[256] = (float)s0;
  }
}

// ---- fused score + topk + gather, one block per graph ----
__global__ __launch_bounds__(512) void k_topk(
    const float* __restrict__ feat, const float* __restrict__ sv,
    const float* __restrict__ cA, const float* __restrict__ cB,
    float* __restrict__ out) {
  __shared__ float svl[256];
  __shared__ float ss[NPG];
  __shared__ int sel[KKEEP];
  __shared__ float gate[KKEEP];
  const int g = blockIdx.x;
  const int t = threadIdx.x;
  if (t < 256) svl[t] = sv[t];
  __syncthreads();
  // score for node g*512+t
  const float* fr = &feat[((size_t)g * NPG + t) * 256];
  float4 a0 = make_float4(0.f, 0.f, 0.f, 0.f);
  float4 a1 = make_float4(0.f, 0.f, 0.f, 0.f);
  for (int c = 0; c < 256; c += 8) {
    float4 f0 = *(const float4*)&fr[c];
    float4 f1 = *(const float4*)&fr[c + 4];
    float4 w0 = *(const float4*)&svl[c];
    float4 w1 = *(const float4*)&svl[c + 4];
    a0.x = fmaf(f0.x, w0.x, a0.x); a1.x = fmaf(f1.x, w1.x, a1.x);
    a0.y = fmaf(f0.y, w0.y, a0.y); a1.y = fmaf(f1.y, w1.y, a1.y);
    a0.z = fmaf(f0.z, w0.z, a0.z); a1.z = fmaf(f1.z, w1.z, a1.z);
    a0.w = fmaf(f0.w, w0.w, a0.w); a1.w = fmaf(f1.w, w1.w, a1.w);
  }
  float s = (a0.x + a1.x) + (a0.y + a1.y) + (a0.z + a1.z) + (a0.w + a1.w) + sv[256];
  ss[t] = s;
  __syncthreads();
  int rank = 0;
  for (int j = 0; j < NPG; j++) {
    float sj = ss[j];
    rank += (sj > s || (sj == s && j < t)) ? 1 : 0;
  }
  if (rank < KKEEP) {
    sel[rank] = t;
    gate[rank] = tanhf(s);
  }
  __syncthreads();
  for (int idx = t; idx < KKEEP * 64; idx += 512) {
    int r = idx >> 6;
    int c4 = (idx & 63) * 4;
    int node = g * NPG + sel[r];
    float4 f = *(const float4*)&feat[(size_t)node * 256 + c4];
    float4 a = *(const float4*)&cA[c4];
    float4 b = *(const float4*)&cB[c4];
    float tg = gate[r];
    float4 o;
    o.x = fmaf(f.x, a.x, b.x) * tg;
    o.y = fmaf(f.y, a.y, b.y) * tg;
    o.z = fmaf(f.z, a.z, b.z) * tg;
    o.w = fmaf(f.w, a.w, b.w) * tg;
    *(float4*)&out[(size_t)(g * KKEEP + r) * 256 + c4] = o;
  }
}

extern "C" void kernel_launch(void* const* d_in, const int* in_sizes, int n_in,
                              void* d_out, int out_size, void* d_ws, size_t ws_size,
                              hipStream_t stream) {
  const float* x    = (const float*)d_in[0];
  const int*   ei   = (const int*)d_in[1];
  const float* W    = (const float*)d_in[2];
  const float* attS = (const float*)d_in[3];
  const float* attD = (const float*)d_in[4];
  const float* bias = (const float*)d_in[5];
  const float* gam  = (const float*)d_in[6];
  const float* bet  = (const float*)d_in[7];
  const float* pw   = (const float*)d_in[8];
  float* out = (float*)d_out;
  const int E = in_sizes[1] / 2;

  char* p = (char*)d_ws;
  float* h     = (float*)p; p += (size_t)N_NODES * 256 * 4;
  char* region = p;         p += (size_t)N_NODES * 256 * 4;
  unsigned short* xh = (unsigned short*)region;
  unsigned short* xl = (unsigned short*)(region + (size_t)N_NODES * 256 * 2);
  float* feat  = (float*)region;
  float* a_src = (float*)p; p += (size_t)N_NODES * 4 * 4;
  float* a_dst = (float*)p; p += (size_t)N_NODES * 4 * 4;
  double* psum = (double*)p; p += (size_t)256 * 256 * 8;
  double* psq  = (double*)p; p += (size_t)256 * 256 * 8;
  float* cA    = (float*)p; p += 256 * 4;
  float* cB    = (float*)p; p += 256 * 4;
  float* sv    = (float*)p; p += 260 * 4;
  unsigned short* wth  = (unsigned short*)p; p += (size_t)256 * 256 * 2;
  unsigned short* wtl  = (unsigned short*)p; p += (size_t)256 * 256 * 2;
  unsigned short* wtll = (unsigned short*)p; p += (size_t)256 * 256 * 2;
  int* cnt     = (int*)p;   p += (size_t)N_NODES * 4;
  unsigned short* nbr = (unsigned short*)p; p += (size_t)N_NODES * CAP * 2;

  hipMemsetAsync(cnt, 0, (size_t)N_NODES * 4, stream);
  k_hist_conv<<<4160, 256, 0, stream>>>(ei, E, cnt, nbr, x, W, xh, xl, wth, wtl, wtll);
  k_gemm<<<512, 256, 0, stream>>>(x, xh, xl, wth, wtl, wtll, attS, attD, h, a_src, a_dst);
  k_agg<<<N_NODES / 4, 256, 0, stream>>>(h, a_src, a_dst, cnt, nbr, bias, feat);
  k_bn_partial<<<256, 256, 0, stream>>>(feat, psum, psq);
  k_bn_final<<<1, 1024, 0, stream>>>(psum, psq, gam, bet, pw, cA, cB, sv);
  k_topk<<<NGRAPH, 512, 0, stream>>>(feat, sv, cA, cB, out);
}

// Round 7
// 231.391 us; speedup vs baseline: 1.1245x; 1.1245x over previous
//
#include <hip/hip_runtime.h>
#include <math.h>

#define N_NODES 32768
#define NPG 512
#define NGRAPH 64
#define KKEEP 256
#define CAP 64

typedef __attribute__((ext_vector_type(8))) short short8;
typedef __attribute__((ext_vector_type(4))) float f32x4;

__device__ __forceinline__ unsigned short f2bf(float v) {
  unsigned u = __builtin_bit_cast(unsigned, v);
  u = (u + 0x7FFFu + ((u >> 16) & 1u)) >> 16;
  return (unsigned short)u;
}
__device__ __forceinline__ float bf2f(unsigned short u) {
  unsigned v = ((unsigned)u) << 16;
  return __builtin_bit_cast(float, v);
}

// ---- merged: edge bucketing (blocks 0..2047) + x/W split-bf16 convert ----
__global__ __launch_bounds__(256) void k_hist_conv(
    const int* __restrict__ ei, int E, int* __restrict__ cnt,
    unsigned short* __restrict__ nbr,
    const float* __restrict__ x, const float* __restrict__ W,
    unsigned short* __restrict__ xh, unsigned short* __restrict__ xl,
    unsigned short* __restrict__ wth, unsigned short* __restrict__ wtl,
    unsigned short* __restrict__ wtll) {
  const int t = threadIdx.x;
  if (blockIdx.x < 2048) {
    int e = blockIdx.x * 256 + t;
    if (e < E) {
      int s = ei[e];
      int d = ei[E + e];
      int slot = atomicAdd(&cnt[d], 1);
      if (slot < CAP) nbr[(size_t)d * CAP + slot] = (unsigned short)(s & (NPG - 1));
    }
  } else if (blockIdx.x < 4096) {
    size_t base = ((size_t)(blockIdx.x - 2048) * 256 + t) * 16;
    unsigned short hb[16], lb[16];
#pragma unroll
    for (int g = 0; g < 4; g++) {
      float4 v = *(const float4*)&x[base + g * 4];
      float f[4] = {v.x, v.y, v.z, v.w};
#pragma unroll
      for (int j = 0; j < 4; j++) {
        unsigned short hh = f2bf(f[j]);
        float e1 = f[j] - bf2f(hh);          // exact
        hb[g * 4 + j] = hh;
        lb[g * 4 + j] = f2bf(e1);
      }
    }
    *(uint4*)&xh[base] = *(uint4*)&hb[0];
    *(uint4*)&xh[base + 8] = *(uint4*)&hb[8];
    *(uint4*)&xl[base] = *(uint4*)&lb[0];
    *(uint4*)&xl[base + 8] = *(uint4*)&lb[8];
  } else {
    int bw = blockIdx.x - 4096;              // 0..63
    int n = bw * 4 + (t >> 6);               // output col of W
    int k = (t & 63) * 4;
    unsigned short hb[4], lb[4], qb[4];
#pragma unroll
    for (int j = 0; j < 4; j++) {
      float v = W[(size_t)(k + j) * 256 + n];
      unsigned short hh = f2bf(v);
      float e1 = v - bf2f(hh);               // exact
      unsigned short ll = f2bf(e1);
      float e2 = e1 - bf2f(ll);              // exact
      hb[j] = hh; lb[j] = ll; qb[j] = f2bf(e2);
    }
    *(uint2*)&wth[(size_t)n * 256 + k] = *(uint2*)&hb[0];
    *(uint2*)&wtl[(size_t)n * 256 + k] = *(uint2*)&lb[0];
    *(uint2*)&wtll[(size_t)n * 256 + k] = *(uint2*)&qb[0];
  }
}

// ---- MFMA split-3 bf16 GEMM: h = x@W (+fused a_src/a_dst) ----
__global__ __launch_bounds__(256) void k_gemm(
    const float* __restrict__ x,
    const unsigned short* __restrict__ xhp, const unsigned short* __restrict__ xlp,
    const unsigned short* __restrict__ wth, const unsigned short* __restrict__ wtl,
    const unsigned short* __restrict__ wtll,
    const float* __restrict__ attS, const float* __restrict__ attD,
    float* __restrict__ h, float* __restrict__ a_src, float* __restrict__ a_dst) {
  __shared__ unsigned short As[3][128][40];
  __shared__ unsigned short Bs[3][128][40];
  const int t = threadIdx.x;
  const int mb = blockIdx.x >> 1, nh = blockIdx.x & 1;
  const int row0 = mb * 128;
  const int wid = t >> 6, lane = t & 63;
  const int q = lane >> 4, ln = lane & 15;
  const int wm = (wid >> 1) * 64, wn = (wid & 1) * 64;
  f32x4 acc[4][4] = {};

  for (int kc = 0; kc < 8; kc++) {
    const int k0 = kc * 32;
#pragma unroll
    for (int i = 0; i < 2; i++) {
      int c = i * 256 + t;
      int r = c >> 2, ko = (c & 3) * 8;
      size_t ga = (size_t)(row0 + r) * 256 + k0 + ko;
      uint4 vh = *(const uint4*)&xhp[ga];
      uint4 vl = *(const uint4*)&xlp[ga];
      *(uint4*)&As[0][r][ko] = vh;
      *(uint4*)&As[1][r][ko] = vl;
      float4 f0 = *(const float4*)&x[ga];
      float4 f1 = *(const float4*)&x[ga + 4];
      unsigned short hs[8], ls[8], qs[8];
      *(uint4*)&hs[0] = vh;
      *(uint4*)&ls[0] = vl;
      float ff[8] = {f0.x, f0.y, f0.z, f0.w, f1.x, f1.y, f1.z, f1.w};
#pragma unroll
      for (int j = 0; j < 8; j++)
        qs[j] = f2bf(ff[j] - bf2f(hs[j]) - bf2f(ls[j]));   // exact residual
      *(uint4*)&As[2][r][ko] = *(uint4*)&qs[0];
      size_t gb = (size_t)(nh * 128 + r) * 256 + k0 + ko;
      *(uint4*)&Bs[0][r][ko] = *(const uint4*)&wth[gb];
      *(uint4*)&Bs[1][r][ko] = *(const uint4*)&wtl[gb];
      *(uint4*)&Bs[2][r][ko] = *(const uint4*)&wtll[gb];
    }
    __syncthreads();
    short8 ah[4], al[4], aq[4];
#pragma unroll
    for (int mt = 0; mt < 4; mt++) {
      ah[mt] = *(const short8*)&As[0][wm + mt * 16 + ln][q * 8];
      al[mt] = *(const short8*)&As[1][wm + mt * 16 + ln][q * 8];
      aq[mt] = *(const short8*)&As[2][wm + mt * 16 + ln][q * 8];
    }
#pragma unroll
    for (int nt = 0; nt < 4; nt++) {
      short8 bh = *(const short8*)&Bs[0][wn + nt * 16 + ln][q * 8];
      short8 bl = *(const short8*)&Bs[1][wn + nt * 16 + ln][q * 8];
      short8 bq = *(const short8*)&Bs[2][wn + nt * 16 + ln][q * 8];
#pragma unroll
      for (int mt = 0; mt < 4; mt++) {
        acc[mt][nt] = __builtin_amdgcn_mfma_f32_16x16x32_bf16(ah[mt], bh, acc[mt][nt], 0, 0, 0);
        acc[mt][nt] = __builtin_amdgcn_mfma_f32_16x16x32_bf16(ah[mt], bl, acc[mt][nt], 0, 0, 0);
        acc[mt][nt] = __builtin_amdgcn_mfma_f32_16x16x32_bf16(al[mt], bh, acc[mt][nt], 0, 0, 0);
        acc[mt][nt] = __builtin_amdgcn_mfma_f32_16x16x32_bf16(ah[mt], bq, acc[mt][nt], 0, 0, 0);
        acc[mt][nt] = __builtin_amdgcn_mfma_f32_16x16x32_bf16(al[mt], bl, acc[mt][nt], 0, 0, 0);
        acc[mt][nt] = __builtin_amdgcn_mfma_f32_16x16x32_bf16(aq[mt], bh, acc[mt][nt], 0, 0, 0);
      }
    }
    __syncthreads();
  }
  const int head = nh * 2 + (wid & 1);
  float sA[4], sD[4];
#pragma unroll
  for (int nt = 0; nt < 4; nt++) {
    int n = nh * 128 + wn + nt * 16 + ln;
    sA[nt] = attS[n];
    sD[nt] = attD[n];
  }
#pragma unroll
  for (int mt = 0; mt < 4; mt++) {
#pragma unroll
    for (int reg = 0; reg < 4; reg++) {
      int m = row0 + wm + mt * 16 + q * 4 + reg;
      float ps = 0.f, pd = 0.f;
#pragma unroll
      for (int nt = 0; nt < 4; nt++) {
        float v = acc[mt][nt][reg];
        h[(size_t)m * 256 + nh * 128 + wn + nt * 16 + ln] = v;
        ps = fmaf(v, sA[nt], ps);
        pd = fmaf(v, sD[nt], pd);
      }
#pragma unroll
      for (int d = 1; d < 16; d <<= 1) {
        ps += __shfl_xor(ps, d, 16);
        pd += __shfl_xor(pd, d, 16);
      }
      if (ln == 0) {
        a_src[m * 4 + head] = ps;
        a_dst[m * 4 + head] = pd;
      }
    }
  }
}

// ---- aggregation: softmax weights computed once, broadcast via LDS ----
__global__ __launch_bounds__(256) void k_agg(
    const float* __restrict__ h, const float* __restrict__ a_src,
    const float* __restrict__ a_dst, const int* __restrict__ cnt,
    const unsigned short* __restrict__ nbr, const float* __restrict__ bias,
    float* __restrict__ feat) {
  __shared__ float p_lds[4][68][4];
  __shared__ int s_lds[4][68];
  const int wv = threadIdx.x >> 6;
  const int lane = threadIdx.x & 63;
  int nb = (blockIdx.x & 7) * (N_NODES / 4 / 8) + (blockIdx.x >> 3);
  const int node = nb * 4 + wv;
  const int head = lane >> 4;
  const int li = lane & 15;
  const int c0 = lane * 4;
  const int base = node & ~(NPG - 1);
  const float ad = a_dst[node * 4 + head];
  int n = cnt[node];
  if (n > CAP) n = CAP;
  float e_reg[5];
  int srcs[5];
  int nit = 0;
  float m = -1e30f;
  for (int j = li; j <= n; j += 16) {
    int s = (j < n) ? base + (int)nbr[(size_t)node * CAP + j] : node;
    float e = a_src[s * 4 + head] + ad;
    e = (e > 0.f) ? e : 0.2f * e;
    srcs[nit] = s;
    e_reg[nit++] = e;
    m = fmaxf(m, e);
  }
#pragma unroll
  for (int d = 1; d < 16; d <<= 1) m = fmaxf(m, __shfl_xor(m, d, 16));
  float l = 0.f;
  for (int i = 0; i < nit; i++) {
    int j = li + i * 16;
    float p = __expf(e_reg[i] - m);
    l += p;
    p_lds[wv][j][head] = p;
    if (head == 0) s_lds[wv][j] = srcs[i];
  }
#pragma unroll
  for (int d = 1; d < 16; d <<= 1) l += __shfl_xor(l, d, 16);
  const float linv = 1.f / (l + 1e-16f);
  __builtin_amdgcn_s_waitcnt(0);
  float4 acc0 = make_float4(0.f, 0.f, 0.f, 0.f);
  float4 acc1 = make_float4(0.f, 0.f, 0.f, 0.f);
  int j = 0;
  for (; j + 1 <= n; j += 2) {
    float p0 = p_lds[wv][j][head];
    float p1 = p_lds[wv][j + 1][head];
    int s0 = s_lds[wv][j];
    int s1 = s_lds[wv][j + 1];
    float4 h0 = *(const float4*)&h[(size_t)s0 * 256 + c0];
    float4 h1 = *(const float4*)&h[(size_t)s1 * 256 + c0];
    acc0.x = fmaf(p0, h0.x, acc0.x); acc1.x = fmaf(p1, h1.x, acc1.x);
    acc0.y = fmaf(p0, h0.y, acc0.y); acc1.y = fmaf(p1, h1.y, acc1.y);
    acc0.z = fmaf(p0, h0.z, acc0.z); acc1.z = fmaf(p1, h1.z, acc1.z);
    acc0.w = fmaf(p0, h0.w, acc0.w); acc1.w = fmaf(p1, h1.w, acc1.w);
  }
  if (j <= n) {
    float p0 = p_lds[wv][j][head];
    int s0 = s_lds[wv][j];
    float4 h0 = *(const float4*)&h[(size_t)s0 * 256 + c0];
    acc0.x = fmaf(p0, h0.x, acc0.x);
    acc0.y = fmaf(p0, h0.y, acc0.y);
    acc0.z = fmaf(p0, h0.z, acc0.z);
    acc0.w = fmaf(p0, h0.w, acc0.w);
  }
  const float4 b4 = *(const float4*)&bias[c0];
  float4 o;
  o.x = fmaxf(fmaf(acc0.x + acc1.x, linv, b4.x), 0.f);
  o.y = fmaxf(fmaf(acc0.y + acc1.y, linv, b4.y), 0.f);
  o.z = fmaxf(fmaf(acc0.z + acc1.z, linv, b4.z), 0.f);
  o.w = fmaxf(fmaf(acc0.w + acc1.w, linv, b4.w), 0.f);
  *(float4*)&feat[(size_t)node * 256 + c0] = o;
}

// ---- BN stats ----
__global__ __launch_bounds__(256) void k_bn_partial(const float* __restrict__ feat,
                                                    double* __restrict__ psum,
                                                    double* __restrict__ psq) {
  const int c = threadIdx.x;
  const int r0 = blockIdx.x * 128;
  double s = 0.0, q = 0.0;
  for (int i = 0; i < 128; i++) {
    double v = (double)feat[(size_t)(r0 + i) * 256 + c];
    s += v;
    q += v * v;
  }
  psum[blockIdx.x * 256 + c] = s;
  psq[blockIdx.x * 256 + c] = q;
}

// cA/cB for output BN; sv[c]=cA*pwn, sv[256]=sum(cB*pwn) for the score
__global__ __launch_bounds__(1024) void k_bn_final(
    const double* __restrict__ psum, const double* __restrict__ psq,
    const float* __restrict__ gam, const float* __restrict__ bet,
    const float* __restrict__ pw, float* __restrict__ cA, float* __restrict__ cB,
    float* __restrict__ sv) {
  __shared__ double reds[4][256];
  __shared__ double redq[4][256];
  __shared__ double wsq[256];
  __shared__ double sb[256];
  const int t = threadIdx.x;
  const int c = t & 255, sl = t >> 8;
  double s = 0.0, q = 0.0;
  for (int i = sl * 64; i < sl * 64 + 64; i++) {
    s += psum[i * 256 + c];
    q += psq[i * 256 + c];
  }
  reds[sl][c] = s;
  redq[sl][c] = q;
  if (sl == 0) {
    double w = (double)pw[c];
    wsq[c] = w * w;
  }
  __syncthreads();
  if (t == 0) {
    double nn = 0.0;
    for (int i = 0; i < 256; i++) nn += wsq[i];
    wsq[0] = sqrt(nn);
  }
  __syncthreads();
  if (sl == 0) {
    s = reds[0][c] + reds[1][c] + reds[2][c] + reds[3][c];
    q = redq[0][c] + redq[1][c] + redq[2][c] + redq[3][c];
    double mean = s / (double)N_NODES;
    double var = q / (double)N_NODES - mean * mean;
    double a = (double)gam[c] / sqrt(var + 1e-5);
    double cb = (double)bet[c] - mean * a;
    cA[c] = (float)a;
    cB[c] = (float)cb;
    double pwnv = (double)pw[c] / wsq[0];
    sv[c] = (float)(a * pwnv);
    sb[c] = cb * pwnv;
  }
  __syncthreads();
  if (t == 0) {
    double s0 = 0.0;
    for (int i = 0; i < 256; i++) s0 += sb[i];
    sv[256] = (float)s0;
  }
}

// ---- score: one wave per node, coalesced ----
__global__ __launch_bounds__(256) void k_score(
    const float* __restrict__ feat, const float* __restrict__ sv,
    float* __restrict__ score) {
  const int lane = threadIdx.x & 63;
  const int node = blockIdx.x * 4 + (threadIdx.x >> 6);
  const int c0 = lane * 4;
  float4 f = *(const float4*)&feat[(size_t)node * 256 + c0];
  float4 w = *(const float4*)&sv[c0];
  float p = f.x * w.x + f.y * w.y + f.z * w.z + f.w * w.w;
#pragma unroll
  for (int d = 1; d < 64; d <<= 1) p += __shfl_xor(p, d, 64);
  if (lane == 0) score[node] = p + sv[256];
}

// ---- topk + gather: 8 blocks per graph, 64 nodes each ----
__global__ __launch_bounds__(256) void k_topk(
    const float* __restrict__ score, const float* __restrict__ feat,
    const float* __restrict__ cA, const float* __restrict__ cB,
    float* __restrict__ out) {
  __shared__ float ss[NPG];
  __shared__ int rnk[64];
  __shared__ float gt[64];
  const int g = blockIdx.x >> 3;
  const int part = blockIdx.x & 7;
  const int t = threadIdx.x;
  ss[t] = score[g * NPG + t];
  ss[t + 256] = score[g * NPG + t + 256];
  __syncthreads();
  // 4 threads per node scan 128 scores each
  const int ln = t & 3;
  const int ndl = part * 64 + (t >> 2);   // local node id in graph
  const float s = ss[ndl];
  int rank = 0;
  for (int j = ln * 128; j < ln * 128 + 128; j++) {
    float sj = ss[j];
    rank += (sj > s || (sj == s && j < ndl)) ? 1 : 0;
  }
  rank += __shfl_xor(rank, 1);
  rank += __shfl_xor(rank, 2);
  if (ln == 0) {
    rnk[t >> 2] = rank;
    gt[t >> 2] = tanhf(s);
  }
  __syncthreads();
  // gather: 64 local rows, 64 lanes per row
  for (int idx = t; idx < 64 * 64; idx += 256) {
    int r = idx >> 6;            // local node 0..63
    int rank2 = rnk[r];
    if (rank2 < KKEEP) {
      int c4 = (idx & 63) * 4;
      int node = g * NPG + part * 64 + r;
      float4 f = *(const float4*)&feat[(size_t)node * 256 + c4];
      float4 a = *(const float4*)&cA[c4];
      float4 b = *(const float4*)&cB[c4];
      float tg = gt[r];
      float4 o;
      o.x = fmaf(f.x, a.x, b.x) * tg;
      o.y = fmaf(f.y, a.y, b.y) * tg;
      o.z = fmaf(f.z, a.z, b.z) * tg;
      o.w = fmaf(f.w, a.w, b.w) * tg;
      *(float4*)&out[(size_t)(g * KKEEP + rank2) * 256 + c4] = o;
    }
  }
}

extern "C" void kernel_launch(void* const* d_in, const int* in_sizes, int n_in,
                              void* d_out, int out_size, void* d_ws, size_t ws_size,
                              hipStream_t stream) {
  const float* x    = (const float*)d_in[0];
  const int*   ei   = (const int*)d_in[1];
  const float* W    = (const float*)d_in[2];
  const float* attS = (const float*)d_in[3];
  const float* attD = (const float*)d_in[4];
  const float* bias = (const float*)d_in[5];
  const float* gam  = (const float*)d_in[6];
  const float* bet  = (const float*)d_in[7];
  const float* pw   = (const float*)d_in[8];
  float* out = (float*)d_out;
  const int E = in_sizes[1] / 2;

  char* p = (char*)d_ws;
  float* h     = (float*)p; p += (size_t)N_NODES * 256 * 4;
  char* region = p;         p += (size_t)N_NODES * 256 * 4;
  unsigned short* xh = (unsigned short*)region;
  unsigned short* xl = (unsigned short*)(region + (size_t)N_NODES * 256 * 2);
  float* feat  = (float*)region;
  float* a_src = (float*)p; p += (size_t)N_NODES * 4 * 4;
  float* a_dst = (float*)p; p += (size_t)N_NODES * 4 * 4;
  float* score = (float*)p; p += (size_t)N_NODES * 4;
  double* psum = (double*)p; p += (size_t)256 * 256 * 8;
  double* psq  = (double*)p; p += (size_t)256 * 256 * 8;
  float* cA    = (float*)p; p += 256 * 4;
  float* cB    = (float*)p; p += 256 * 4;
  float* sv    = (float*)p; p += 260 * 4;
  unsigned short* wth  = (unsigned short*)p; p += (size_t)256 * 256 * 2;
  unsigned short* wtl  = (unsigned short*)p; p += (size_t)256 * 256 * 2;
  unsigned short* wtll = (unsigned short*)p; p += (size_t)256 * 256 * 2;
  int* cnt     = (int*)p;   p += (size_t)N_NODES * 4;
  unsigned short* nbr = (unsigned short*)p; p += (size_t)N_NODES * CAP * 2;

  hipMemsetAsync(cnt, 0, (size_t)N_NODES * 4, stream);
  k_hist_conv<<<4160, 256, 0, stream>>>(ei, E, cnt, nbr, x, W, xh, xl, wth, wtl, wtll);
  k_gemm<<<512, 256, 0, stream>>>(x, xh, xl, wth, wtl, wtll, attS, attD, h, a_src, a_dst);
  k_agg<<<N_NODES / 4, 256, 0, stream>>>(h, a_src, a_dst, cnt, nbr, bias, feat);
  k_bn_partial<<<256, 256, 0, stream>>>(feat, psum, psq);
  k_bn_final<<<1, 1024, 0, stream>>>(psum, psq, gam, bet, pw, cA, cB, sv);
  k_score<<<N_NODES / 4, 256, 0, stream>>>(feat, sv, score);
  k_topk<<<NGRAPH * 8, 256, 0, stream>>>(score, feat, cA, cB, out);
}

// Round 8
// 222.132 us; speedup vs baseline: 1.1714x; 1.0417x over previous
//
#include <hip/hip_runtime.h>
#include <math.h>

#define N_NODES 32768
#define NPG 512
#define NGRAPH 64
#define KKEEP 256
#define CAP 64

typedef __attribute__((ext_vector_type(8))) short short8;
typedef __attribute__((ext_vector_type(4))) float f32x4;

__device__ __forceinline__ unsigned short f2bf(float v) {
  unsigned u = __builtin_bit_cast(unsigned, v);
  u = (u + 0x7FFFu + ((u >> 16) & 1u)) >> 16;
  return (unsigned short)u;
}
__device__ __forceinline__ float bf2f(unsigned short u) {
  unsigned v = ((unsigned)u) << 16;
  return __builtin_bit_cast(float, v);
}

// ---- merged: edge bucketing (blocks 0..2047) + x/W split-bf16 convert ----
__global__ __launch_bounds__(256) void k_hist_conv(
    const int* __restrict__ ei, int E, int* __restrict__ cnt,
    unsigned short* __restrict__ nbr,
    const float* __restrict__ x, const float* __restrict__ W,
    unsigned short* __restrict__ xh, unsigned short* __restrict__ xl,
    unsigned short* __restrict__ wth, unsigned short* __restrict__ wtl,
    unsigned short* __restrict__ wtll) {
  const int t = threadIdx.x;
  if (blockIdx.x < 2048) {
    int e = blockIdx.x * 256 + t;
    if (e < E) {
      int s = ei[e];
      int d = ei[E + e];
      int slot = atomicAdd(&cnt[d], 1);
      if (slot < CAP) nbr[(size_t)d * CAP + slot] = (unsigned short)(s & (NPG - 1));
    }
  } else if (blockIdx.x < 4096) {
    size_t base = ((size_t)(blockIdx.x - 2048) * 256 + t) * 16;
    unsigned short hb[16], lb[16];
#pragma unroll
    for (int g = 0; g < 4; g++) {
      float4 v = *(const float4*)&x[base + g * 4];
      float f[4] = {v.x, v.y, v.z, v.w};
#pragma unroll
      for (int j = 0; j < 4; j++) {
        unsigned short hh = f2bf(f[j]);
        float e1 = f[j] - bf2f(hh);          // exact
        hb[g * 4 + j] = hh;
        lb[g * 4 + j] = f2bf(e1);
      }
    }
    *(uint4*)&xh[base] = *(uint4*)&hb[0];
    *(uint4*)&xh[base + 8] = *(uint4*)&hb[8];
    *(uint4*)&xl[base] = *(uint4*)&lb[0];
    *(uint4*)&xl[base + 8] = *(uint4*)&lb[8];
  } else {
    int bw = blockIdx.x - 4096;              // 0..63
    int n = bw * 4 + (t >> 6);               // output col of W
    int k = (t & 63) * 4;
    unsigned short hb[4], lb[4], qb[4];
#pragma unroll
    for (int j = 0; j < 4; j++) {
      float v = W[(size_t)(k + j) * 256 + n];
      unsigned short hh = f2bf(v);
      float e1 = v - bf2f(hh);               // exact
      unsigned short ll = f2bf(e1);
      float e2 = e1 - bf2f(ll);              // exact
      hb[j] = hh; lb[j] = ll; qb[j] = f2bf(e2);
    }
    *(uint2*)&wth[(size_t)n * 256 + k] = *(uint2*)&hb[0];
    *(uint2*)&wtl[(size_t)n * 256 + k] = *(uint2*)&lb[0];
    *(uint2*)&wtll[(size_t)n * 256 + k] = *(uint2*)&qb[0];
  }
}

// ---- MFMA split-3 bf16 GEMM, k-chunk-major LDS, LDS-transpose epilogue ----
// LDS: A chunks [3][4][128] of 16B at 0; B chunks at ushort offset 12288. 48KB.
__global__ __launch_bounds__(256) void k_gemm(
    const float* __restrict__ x,
    const unsigned short* __restrict__ xhp, const unsigned short* __restrict__ xlp,
    const unsigned short* __restrict__ wth, const unsigned short* __restrict__ wtl,
    const unsigned short* __restrict__ wtll,
    const float* __restrict__ attS, const float* __restrict__ attD,
    float* __restrict__ h, float* __restrict__ a_src, float* __restrict__ a_dst) {
  __shared__ unsigned short lds[24576];      // 48 KB
  const int t = threadIdx.x;
  const int bid = blockIdx.x;
  // XCD pairing: both nh halves of an mb land on the same XCD (bid%8);
  // XCD c owns mb in [32c, 32c+32) -> A rows [4096c, 4096c+4096), matches k_agg.
  const int mb = (bid & 7) * 32 + (bid >> 4);
  const int nh = (bid >> 3) & 1;
  const int row0 = mb * 128;
  const int wid = t >> 6, lane = t & 63;
  const int q = lane >> 4, ln = lane & 15;
  const int wm = (wid >> 1) * 64, wn = (wid & 1) * 64;
  f32x4 acc[4][4] = {};

  for (int kc = 0; kc < 8; kc++) {
    const int k0 = kc * 32;
#pragma unroll
    for (int i = 0; i < 2; i++) {
      int c = i * 256 + t;
      int r = c >> 2, cq = c & 3;
      size_t ga = (size_t)(row0 + r) * 256 + k0 + cq * 8;
      uint4 vh = *(const uint4*)&xhp[ga];
      uint4 vl = *(const uint4*)&xlp[ga];
      *(uint4*)&lds[((0 * 4 + cq) * 128 + r) * 8] = vh;
      *(uint4*)&lds[((1 * 4 + cq) * 128 + r) * 8] = vl;
      float4 f0 = *(const float4*)&x[ga];
      float4 f1 = *(const float4*)&x[ga + 4];
      unsigned short hs[8], ls[8], qs[8];
      *(uint4*)&hs[0] = vh;
      *(uint4*)&ls[0] = vl;
      float ff[8] = {f0.x, f0.y, f0.z, f0.w, f1.x, f1.y, f1.z, f1.w};
#pragma unroll
      for (int j = 0; j < 8; j++)
        qs[j] = f2bf(ff[j] - bf2f(hs[j]) - bf2f(ls[j]));   // exact residual
      *(uint4*)&lds[((2 * 4 + cq) * 128 + r) * 8] = *(uint4*)&qs[0];
      size_t gb = (size_t)(nh * 128 + r) * 256 + k0 + cq * 8;
      *(uint4*)&lds[12288 + ((0 * 4 + cq) * 128 + r) * 8] = *(const uint4*)&wth[gb];
      *(uint4*)&lds[12288 + ((1 * 4 + cq) * 128 + r) * 8] = *(const uint4*)&wtl[gb];
      *(uint4*)&lds[12288 + ((2 * 4 + cq) * 128 + r) * 8] = *(const uint4*)&wtll[gb];
    }
    __syncthreads();
    short8 ah[4], al[4], aq[4];
#pragma unroll
    for (int mt = 0; mt < 4; mt++) {
      int r = wm + mt * 16 + ln;
      ah[mt] = *(const short8*)&lds[((0 * 4 + q) * 128 + r) * 8];
      al[mt] = *(const short8*)&lds[((1 * 4 + q) * 128 + r) * 8];
      aq[mt] = *(const short8*)&lds[((2 * 4 + q) * 128 + r) * 8];
    }
#pragma unroll
    for (int nt = 0; nt < 4; nt++) {
      int r = wn + nt * 16 + ln;
      short8 bh = *(const short8*)&lds[12288 + ((0 * 4 + q) * 128 + r) * 8];
      short8 bl = *(const short8*)&lds[12288 + ((1 * 4 + q) * 128 + r) * 8];
      short8 bq = *(const short8*)&lds[12288 + ((2 * 4 + q) * 128 + r) * 8];
#pragma unroll
      for (int mt = 0; mt < 4; mt++) {
        acc[mt][nt] = __builtin_amdgcn_mfma_f32_16x16x32_bf16(ah[mt], bh, acc[mt][nt], 0, 0, 0);
        acc[mt][nt] = __builtin_amdgcn_mfma_f32_16x16x32_bf16(ah[mt], bl, acc[mt][nt], 0, 0, 0);
        acc[mt][nt] = __builtin_amdgcn_mfma_f32_16x16x32_bf16(al[mt], bh, acc[mt][nt], 0, 0, 0);
        acc[mt][nt] = __builtin_amdgcn_mfma_f32_16x16x32_bf16(ah[mt], bq, acc[mt][nt], 0, 0, 0);
        acc[mt][nt] = __builtin_amdgcn_mfma_f32_16x16x32_bf16(al[mt], bl, acc[mt][nt], 0, 0, 0);
        acc[mt][nt] = __builtin_amdgcn_mfma_f32_16x16x32_bf16(aq[mt], bh, acc[mt][nt], 0, 0, 0);
      }
    }
    __syncthreads();
  }
  // epilogue: store h; att partials via LDS transpose (aliased over staging)
  const int head = nh * 2 + (wid & 1);
  float sA[4], sD[4];
#pragma unroll
  for (int nt = 0; nt < 4; nt++) {
    int n = nh * 128 + wn + nt * 16 + ln;
    sA[nt] = attS[n];
    sD[nt] = attD[n];
  }
  float2* epi = (float2*)lds;   // [wv][q][rr(16)][18] float2
#pragma unroll
  for (int mt = 0; mt < 4; mt++) {
#pragma unroll
    for (int reg = 0; reg < 4; reg++) {
      int m = row0 + wm + mt * 16 + q * 4 + reg;
      float ps = 0.f, pd = 0.f;
#pragma unroll
      for (int nt = 0; nt < 4; nt++) {
        float v = acc[mt][nt][reg];
        h[(size_t)m * 256 + nh * 128 + wn + nt * 16 + ln] = v;
        ps = fmaf(v, sA[nt], ps);
        pd = fmaf(v, sD[nt], pd);
      }
      epi[(((wid * 4 + q) * 16) + mt * 4 + reg) * 18 + ln] = make_float2(ps, pd);
    }
  }
  __syncthreads();
  {
    const int q2 = lane >> 4, rr = lane & 15;
    const int base = (((wid * 4 + q2) * 16) + rr) * 18;
    float ps = 0.f, pd = 0.f;
#pragma unroll
    for (int i = 0; i < 16; i++) {
      float2 v = epi[base + i];
      ps += v.x;
      pd += v.y;
    }
    int m = row0 + wm + (rr >> 2) * 16 + q2 * 4 + (rr & 3);
    a_src[m * 4 + head] = ps;
    a_dst[m * 4 + head] = pd;
  }
}

// ---- aggregation: softmax weights computed once, broadcast via LDS ----
__global__ __launch_bounds__(256) void k_agg(
    const float* __restrict__ h, const float* __restrict__ a_src,
    const float* __restrict__ a_dst, const int* __restrict__ cnt,
    const unsigned short* __restrict__ nbr, const float* __restrict__ bias,
    float* __restrict__ feat) {
  __shared__ float p_lds[4][68][4];
  __shared__ int s_lds[4][68];
  const int wv = threadIdx.x >> 6;
  const int lane = threadIdx.x & 63;
  int nb = (blockIdx.x & 7) * (N_NODES / 4 / 8) + (blockIdx.x >> 3);
  const int node = nb * 4 + wv;
  const int head = lane >> 4;
  const int li = lane & 15;
  const int c0 = lane * 4;
  const int base = node & ~(NPG - 1);
  const float ad = a_dst[node * 4 + head];
  int n = cnt[node];
  if (n > CAP) n = CAP;
  float e_reg[5];
  int srcs[5];
  int nit = 0;
  float m = -1e30f;
  for (int j = li; j <= n; j += 16) {
    int s = (j < n) ? base + (int)nbr[(size_t)node * CAP + j] : node;
    float e = a_src[s * 4 + head] + ad;
    e = (e > 0.f) ? e : 0.2f * e;
    srcs[nit] = s;
    e_reg[nit++] = e;
    m = fmaxf(m, e);
  }
#pragma unroll
  for (int d = 1; d < 16; d <<= 1) m = fmaxf(m, __shfl_xor(m, d, 16));
  float l = 0.f;
  for (int i = 0; i < nit; i++) {
    int j = li + i * 16;
    float p = __expf(e_reg[i] - m);
    l += p;
    p_lds[wv][j][head] = p;
    if (head == 0) s_lds[wv][j] = srcs[i];
  }
#pragma unroll
  for (int d = 1; d < 16; d <<= 1) l += __shfl_xor(l, d, 16);
  const float linv = 1.f / (l + 1e-16f);
  __builtin_amdgcn_s_waitcnt(0);
  float4 acc0 = make_float4(0.f, 0.f, 0.f, 0.f);
  float4 acc1 = make_float4(0.f, 0.f, 0.f, 0.f);
  int j = 0;
  for (; j + 1 <= n; j += 2) {
    float p0 = p_lds[wv][j][head];
    float p1 = p_lds[wv][j + 1][head];
    int s0 = s_lds[wv][j];
    int s1 = s_lds[wv][j + 1];
    float4 h0 = *(const float4*)&h[(size_t)s0 * 256 + c0];
    float4 h1 = *(const float4*)&h[(size_t)s1 * 256 + c0];
    acc0.x = fmaf(p0, h0.x, acc0.x); acc1.x = fmaf(p1, h1.x, acc1.x);
    acc0.y = fmaf(p0, h0.y, acc0.y); acc1.y = fmaf(p1, h1.y, acc1.y);
    acc0.z = fmaf(p0, h0.z, acc0.z); acc1.z = fmaf(p1, h1.z, acc1.z);
    acc0.w = fmaf(p0, h0.w, acc0.w); acc1.w = fmaf(p1, h1.w, acc1.w);
  }
  if (j <= n) {
    float p0 = p_lds[wv][j][head];
    int s0 = s_lds[wv][j];
    float4 h0 = *(const float4*)&h[(size_t)s0 * 256 + c0];
    acc0.x = fmaf(p0, h0.x, acc0.x);
    acc0.y = fmaf(p0, h0.y, acc0.y);
    acc0.z = fmaf(p0, h0.z, acc0.z);
    acc0.w = fmaf(p0, h0.w, acc0.w);
  }
  const float4 b4 = *(const float4*)&bias[c0];
  float4 o;
  o.x = fmaxf(fmaf(acc0.x + acc1.x, linv, b4.x), 0.f);
  o.y = fmaxf(fmaf(acc0.y + acc1.y, linv, b4.y), 0.f);
  o.z = fmaxf(fmaf(acc0.z + acc1.z, linv, b4.z), 0.f);
  o.w = fmaxf(fmaf(acc0.w + acc1.w, linv, b4.w), 0.f);
  *(float4*)&feat[(size_t)node * 256 + c0] = o;
}

// ---- BN stats ----
__global__ __launch_bounds__(256) void k_bn_partial(const float* __restrict__ feat,
                                                    double* __restrict__ psum,
                                                    double* __restrict__ psq) {
  const int c = threadIdx.x;
  const int r0 = blockIdx.x * 128;
  double s = 0.0, q = 0.0;
  for (int i = 0; i < 128; i++) {
    double v = (double)feat[(size_t)(r0 + i) * 256 + c];
    s += v;
    q += v * v;
  }
  psum[blockIdx.x * 256 + c] = s;
  psq[blockIdx.x * 256 + c] = q;
}

// cA/cB for output BN; sv[c]=cA*pwn, sv[256]=sum(cB*pwn) for the score
__global__ __launch_bounds__(1024) void k_bn_final(
    const double* __restrict__ psum, const double* __restrict__ psq,
    const float* __restrict__ gam, const float* __restrict__ bet,
    const float* __restrict__ pw, float* __restrict__ cA, float* __restrict__ cB,
    float* __restrict__ sv) {
  __shared__ double reds[4][256];
  __shared__ double redq[4][256];
  __shared__ double wsq[256];
  __shared__ double sb[256];
  const int t = threadIdx.x;
  const int c = t & 255, sl = t >> 8;
  double s = 0.0, q = 0.0;
  for (int i = sl * 64; i < sl * 64 + 64; i++) {
    s += psum[i * 256 + c];
    q += psq[i * 256 + c];
  }
  reds[sl][c] = s;
  redq[sl][c] = q;
  if (sl == 0) {
    double w = (double)pw[c];
    wsq[c] = w * w;
  }
  __syncthreads();
  if (t == 0) {
    double nn = 0.0;
    for (int i = 0; i < 256; i++) nn += wsq[i];
    wsq[0] = sqrt(nn);
  }
  __syncthreads();
  if (sl == 0) {
    s = reds[0][c] + reds[1][c] + reds[2][c] + reds[3][c];
    q = redq[0][c] + redq[1][c] + redq[2][c] + redq[3][c];
    double mean = s / (double)N_NODES;
    double var = q / (double)N_NODES - mean * mean;
    double a = (double)gam[c] / sqrt(var + 1e-5);
    double cb = (double)bet[c] - mean * a;
    cA[c] = (float)a;
    cB[c] = (float)cb;
    double pwnv = (double)pw[c] / wsq[0];
    sv[c] = (float)(a * pwnv);
    sb[c] = cb * pwnv;
  }
  __syncthreads();
  if (t == 0) {
    double s0 = 0.0;
    for (int i = 0; i < 256; i++) s0 += sb[i];
    sv[256] = (float)s0;
  }
}

// ---- score: one wave per node, coalesced ----
__global__ __launch_bounds__(256) void k_score(
    const float* __restrict__ feat, const float* __restrict__ sv,
    float* __restrict__ score) {
  const int lane = threadIdx.x & 63;
  const int node = blockIdx.x * 4 + (threadIdx.x >> 6);
  const int c0 = lane * 4;
  float4 f = *(const float4*)&feat[(size_t)node * 256 + c0];
  float4 w = *(const float4*)&sv[c0];
  float p = f.x * w.x + f.y * w.y + f.z * w.z + f.w * w.w;
#pragma unroll
  for (int d = 1; d < 64; d <<= 1) p += __shfl_xor(p, d, 64);
  if (lane == 0) score[node] = p + sv[256];
}

// ---- topk + gather: 8 blocks per graph, 64 nodes each ----
__global__ __launch_bounds__(256) void k_topk(
    const float* __restrict__ score, const float* __restrict__ feat,
    const float* __restrict__ cA, const float* __restrict__ cB,
    float* __restrict__ out) {
  __shared__ float ss[NPG];
  __shared__ int rnk[64];
  __shared__ float gt[64];
  const int g = blockIdx.x >> 3;
  const int part = blockIdx.x & 7;
  const int t = threadIdx.x;
  ss[t] = score[g * NPG + t];
  ss[t + 256] = score[g * NPG + t + 256];
  __syncthreads();
  const int ln = t & 3;
  const int ndl = part * 64 + (t >> 2);
  const float s = ss[ndl];
  int rank = 0;
  for (int j = ln * 128; j < ln * 128 + 128; j++) {
    float sj = ss[j];
    rank += (sj > s || (sj == s && j < ndl)) ? 1 : 0;
  }
  rank += __shfl_xor(rank, 1);
  rank += __shfl_xor(rank, 2);
  if (ln == 0) {
    rnk[t >> 2] = rank;
    gt[t >> 2] = tanhf(s);
  }
  __syncthreads();
  for (int idx = t; idx < 64 * 64; idx += 256) {
    int r = idx >> 6;
    int rank2 = rnk[r];
    if (rank2 < KKEEP) {
      int c4 = (idx & 63) * 4;
      int node = g * NPG + part * 64 + r;
      float4 f = *(const float4*)&feat[(size_t)node * 256 + c4];
      float4 a = *(const float4*)&cA[c4];
      float4 b = *(const float4*)&cB[c4];
      float tg = gt[r];
      float4 o;
      o.x = fmaf(f.x, a.x, b.x) * tg;
      o.y = fmaf(f.y, a.y, b.y) * tg;
      o.z = fmaf(f.z, a.z, b.z) * tg;
      o.w = fmaf(f.w, a.w, b.w) * tg;
      *(float4*)&out[(size_t)(g * KKEEP + rank2) * 256 + c4] = o;
    }
  }
}

extern "C" void kernel_launch(void* const* d_in, const int* in_sizes, int n_in,
                              void* d_out, int out_size, void* d_ws, size_t ws_size,
                              hipStream_t stream) {
  const float* x    = (const float*)d_in[0];
  const int*   ei   = (const int*)d_in[1];
  const float* W    = (const float*)d_in[2];
  const float* attS = (const float*)d_in[3];
  const float* attD = (const float*)d_in[4];
  const float* bias = (const float*)d_in[5];
  const float* gam  = (const float*)d_in[6];
  const float* bet  = (const float*)d_in[7];
  const float* pw   = (const float*)d_in[8];
  float* out = (float*)d_out;
  const int E = in_sizes[1] / 2;

  char* p = (char*)d_ws;
  float* h     = (float*)p; p += (size_t)N_NODES * 256 * 4;
  char* region = p;         p += (size_t)N_NODES * 256 * 4;
  unsigned short* xh = (unsigned short*)region;
  unsigned short* xl = (unsigned short*)(region + (size_t)N_NODES * 256 * 2);
  float* feat  = (float*)region;
  float* a_src = (float*)p; p += (size_t)N_NODES * 4 * 4;
  float* a_dst = (float*)p; p += (size_t)N_NODES * 4 * 4;
  float* score = (float*)p; p += (size_t)N_NODES * 4;
  double* psum = (double*)p; p += (size_t)256 * 256 * 8;
  double* psq  = (double*)p; p += (size_t)256 * 256 * 8;
  float* cA    = (float*)p; p += 256 * 4;
  float* cB    = (float*)p; p += 256 * 4;
  float* sv    = (float*)p; p += 260 * 4;
  unsigned short* wth  = (unsigned short*)p; p += (size_t)256 * 256 * 2;
  unsigned short* wtl  = (unsigned short*)p; p += (size_t)256 * 256 * 2;
  unsigned short* wtll = (unsigned short*)p; p += (size_t)256 * 256 * 2;
  int* cnt     = (int*)p;   p += (size_t)N_NODES * 4;
  unsigned short* nbr = (unsigned short*)p; p += (size_t)N_NODES * CAP * 2;

  hipMemsetAsync(cnt, 0, (size_t)N_NODES * 4, stream);
  k_hist_conv<<<4160, 256, 0, stream>>>(ei, E, cnt, nbr, x, W, xh, xl, wth, wtl, wtll);
  k_gemm<<<512, 256, 0, stream>>>(x, xh, xl, wth, wtl, wtll, attS, attD, h, a_src, a_dst);
  k_agg<<<N_NODES / 4, 256, 0, stream>>>(h, a_src, a_dst, cnt, nbr, bias, feat);
  k_bn_partial<<<256, 256, 0, stream>>>(feat, psum, psq);
  k_bn_final<<<1, 1024, 0, stream>>>(psum, psq, gam, bet, pw, cA, cB, sv);
  k_score<<<N_NODES / 4, 256, 0, stream>>>(feat, sv, score);
  k_topk<<<NGRAPH * 8, 256, 0, stream>>>(score, feat, cA, cB, out);
}

// Round 9
// 214.400 us; speedup vs baseline: 1.2136x; 1.0361x over previous
//
#include <hip/hip_runtime.h>
#include <math.h>

#define N_NODES 32768
#define NPG 512
#define NGRAPH 64
#define KKEEP 256
#define CAP 64

typedef __attribute__((ext_vector_type(8))) short short8;
typedef __attribute__((ext_vector_type(4))) float f32x4;

__device__ __forceinline__ unsigned short f2bf(float v) {
  unsigned u = __builtin_bit_cast(unsigned, v);
  u = (u + 0x7FFFu + ((u >> 16) & 1u)) >> 16;
  return (unsigned short)u;
}
__device__ __forceinline__ float bf2f(unsigned short u) {
  unsigned v = ((unsigned)u) << 16;
  return __builtin_bit_cast(float, v);
}

// ---- merged: edge bucketing (blocks 0..2047) + W split-bf16 convert ----
__global__ __launch_bounds__(256) void k_hist_conv(
    const int* __restrict__ ei, int E, int* __restrict__ cnt,
    unsigned short* __restrict__ nbr,
    const float* __restrict__ W,
    unsigned short* __restrict__ wth, unsigned short* __restrict__ wtl,
    unsigned short* __restrict__ wtll) {
  const int t = threadIdx.x;
  if (blockIdx.x < 2048) {
    int e = blockIdx.x * 256 + t;
    if (e < E) {
      int s = ei[e];
      int d = ei[E + e];
      int slot = atomicAdd(&cnt[d], 1);
      if (slot < CAP) nbr[(size_t)d * CAP + slot] = (unsigned short)(s & (NPG - 1));
    }
  } else {
    int bw = blockIdx.x - 2048;              // 0..63
    int n = bw * 4 + (t >> 6);               // output col of W
    int k = (t & 63) * 4;
    unsigned short hb[4], lb[4], qb[4];
#pragma unroll
    for (int j = 0; j < 4; j++) {
      float v = W[(size_t)(k + j) * 256 + n];
      unsigned short hh = f2bf(v);
      float e1 = v - bf2f(hh);               // exact
      unsigned short ll = f2bf(e1);
      float e2 = e1 - bf2f(ll);              // exact
      hb[j] = hh; lb[j] = ll; qb[j] = f2bf(e2);
    }
    *(uint2*)&wth[(size_t)n * 256 + k] = *(uint2*)&hb[0];
    *(uint2*)&wtl[(size_t)n * 256 + k] = *(uint2*)&lb[0];
    *(uint2*)&wtll[(size_t)n * 256 + k] = *(uint2*)&qb[0];
  }
}

// ---- MFMA split-3 bf16 GEMM, inline x-split, k-chunk-major LDS ----
// LDS: A chunks [3][4][128] of 16B at 0; B chunks at ushort offset 12288. 48KB.
__global__ __launch_bounds__(256) void k_gemm(
    const float* __restrict__ x,
    const unsigned short* __restrict__ wth, const unsigned short* __restrict__ wtl,
    const unsigned short* __restrict__ wtll,
    const float* __restrict__ attS, const float* __restrict__ attD,
    float* __restrict__ h, float* __restrict__ a_src, float* __restrict__ a_dst) {
  __shared__ unsigned short lds[24576];      // 48 KB
  const int t = threadIdx.x;
  const int bid = blockIdx.x;
  // XCD pairing: both nh halves of an mb land on the same XCD (bid%8);
  // XCD c owns mb in [32c, 32c+32) -> A rows [4096c, 4096c+4096), matches k_agg.
  const int mb = (bid & 7) * 32 + (bid >> 4);
  const int nh = (bid >> 3) & 1;
  const int row0 = mb * 128;
  const int wid = t >> 6, lane = t & 63;
  const int q = lane >> 4, ln = lane & 15;
  const int wm = (wid >> 1) * 64, wn = (wid & 1) * 64;
  f32x4 acc[4][4] = {};

  for (int kc = 0; kc < 8; kc++) {
    const int k0 = kc * 32;
#pragma unroll
    for (int i = 0; i < 2; i++) {
      int c = i * 256 + t;
      int r = c >> 2, cq = c & 3;
      size_t ga = (size_t)(row0 + r) * 256 + k0 + cq * 8;
      float4 f0 = *(const float4*)&x[ga];
      float4 f1 = *(const float4*)&x[ga + 4];
      float ff[8] = {f0.x, f0.y, f0.z, f0.w, f1.x, f1.y, f1.z, f1.w};
      unsigned short hs[8], ls[8], qs[8];
#pragma unroll
      for (int j = 0; j < 8; j++) {
        unsigned short hh = f2bf(ff[j]);
        float e1 = ff[j] - bf2f(hh);         // exact
        unsigned short ll = f2bf(e1);
        float e2 = e1 - bf2f(ll);            // exact
        hs[j] = hh; ls[j] = ll; qs[j] = f2bf(e2);
      }
      *(uint4*)&lds[((0 * 4 + cq) * 128 + r) * 8] = *(uint4*)&hs[0];
      *(uint4*)&lds[((1 * 4 + cq) * 128 + r) * 8] = *(uint4*)&ls[0];
      *(uint4*)&lds[((2 * 4 + cq) * 128 + r) * 8] = *(uint4*)&qs[0];
      size_t gb = (size_t)(nh * 128 + r) * 256 + k0 + cq * 8;
      *(uint4*)&lds[12288 + ((0 * 4 + cq) * 128 + r) * 8] = *(const uint4*)&wth[gb];
      *(uint4*)&lds[12288 + ((1 * 4 + cq) * 128 + r) * 8] = *(const uint4*)&wtl[gb];
      *(uint4*)&lds[12288 + ((2 * 4 + cq) * 128 + r) * 8] = *(const uint4*)&wtll[gb];
    }
    __syncthreads();
    short8 ah[4], al[4], aq[4];
#pragma unroll
    for (int mt = 0; mt < 4; mt++) {
      int r = wm + mt * 16 + ln;
      ah[mt] = *(const short8*)&lds[((0 * 4 + q) * 128 + r) * 8];
      al[mt] = *(const short8*)&lds[((1 * 4 + q) * 128 + r) * 8];
      aq[mt] = *(const short8*)&lds[((2 * 4 + q) * 128 + r) * 8];
    }
#pragma unroll
    for (int nt = 0; nt < 4; nt++) {
      int r = wn + nt * 16 + ln;
      short8 bh = *(const short8*)&lds[12288 + ((0 * 4 + q) * 128 + r) * 8];
      short8 bl = *(const short8*)&lds[12288 + ((1 * 4 + q) * 128 + r) * 8];
      short8 bq = *(const short8*)&lds[12288 + ((2 * 4 + q) * 128 + r) * 8];
#pragma unroll
      for (int mt = 0; mt < 4; mt++) {
        acc[mt][nt] = __builtin_amdgcn_mfma_f32_16x16x32_bf16(ah[mt], bh, acc[mt][nt], 0, 0, 0);
        acc[mt][nt] = __builtin_amdgcn_mfma_f32_16x16x32_bf16(ah[mt], bl, acc[mt][nt], 0, 0, 0);
        acc[mt][nt] = __builtin_amdgcn_mfma_f32_16x16x32_bf16(al[mt], bh, acc[mt][nt], 0, 0, 0);
        acc[mt][nt] = __builtin_amdgcn_mfma_f32_16x16x32_bf16(ah[mt], bq, acc[mt][nt], 0, 0, 0);
        acc[mt][nt] = __builtin_amdgcn_mfma_f32_16x16x32_bf16(al[mt], bl, acc[mt][nt], 0, 0, 0);
        acc[mt][nt] = __builtin_amdgcn_mfma_f32_16x16x32_bf16(aq[mt], bh, acc[mt][nt], 0, 0, 0);
      }
    }
    __syncthreads();
  }
  // epilogue: store h; att partials via LDS transpose (aliased over staging)
  const int head = nh * 2 + (wid & 1);
  float sA[4], sD[4];
#pragma unroll
  for (int nt = 0; nt < 4; nt++) {
    int n = nh * 128 + wn + nt * 16 + ln;
    sA[nt] = attS[n];
    sD[nt] = attD[n];
  }
  float2* epi = (float2*)lds;   // [wv][q][rr(16)][18] float2
#pragma unroll
  for (int mt = 0; mt < 4; mt++) {
#pragma unroll
    for (int reg = 0; reg < 4; reg++) {
      int m = row0 + wm + mt * 16 + q * 4 + reg;
      float ps = 0.f, pd = 0.f;
#pragma unroll
      for (int nt = 0; nt < 4; nt++) {
        float v = acc[mt][nt][reg];
        h[(size_t)m * 256 + nh * 128 + wn + nt * 16 + ln] = v;
        ps = fmaf(v, sA[nt], ps);
        pd = fmaf(v, sD[nt], pd);
      }
      epi[(((wid * 4 + q) * 16) + mt * 4 + reg) * 18 + ln] = make_float2(ps, pd);
    }
  }
  __syncthreads();
  {
    const int q2 = lane >> 4, rr = lane & 15;
    const int base = (((wid * 4 + q2) * 16) + rr) * 18;
    float ps = 0.f, pd = 0.f;
#pragma unroll
    for (int i = 0; i < 16; i++) {
      float2 v = epi[base + i];
      ps += v.x;
      pd += v.y;
    }
    int m = row0 + wm + (rr >> 2) * 16 + q2 * 4 + (rr & 3);
    a_src[m * 4 + head] = ps;
    a_dst[m * 4 + head] = pd;
  }
}

// ---- aggregation: softmax weights computed once, broadcast via LDS ----
__global__ __launch_bounds__(256) void k_agg(
    const float* __restrict__ h, const float* __restrict__ a_src,
    const float* __restrict__ a_dst, const int* __restrict__ cnt,
    const unsigned short* __restrict__ nbr, const float* __restrict__ bias,
    float* __restrict__ feat) {
  __shared__ float p_lds[4][68][4];
  __shared__ int s_lds[4][68];
  const int wv = threadIdx.x >> 6;
  const int lane = threadIdx.x & 63;
  int nb = (blockIdx.x & 7) * (N_NODES / 4 / 8) + (blockIdx.x >> 3);
  const int node = nb * 4 + wv;
  const int head = lane >> 4;
  const int li = lane & 15;
  const int c0 = lane * 4;
  const int base = node & ~(NPG - 1);
  const float ad = a_dst[node * 4 + head];
  int n = cnt[node];
  if (n > CAP) n = CAP;
  float e_reg[5];
  int srcs[5];
  int nit = 0;
  float m = -1e30f;
  for (int j = li; j <= n; j += 16) {
    int s = (j < n) ? base + (int)nbr[(size_t)node * CAP + j] : node;
    float e = a_src[s * 4 + head] + ad;
    e = (e > 0.f) ? e : 0.2f * e;
    srcs[nit] = s;
    e_reg[nit++] = e;
    m = fmaxf(m, e);
  }
#pragma unroll
  for (int d = 1; d < 16; d <<= 1) m = fmaxf(m, __shfl_xor(m, d, 16));
  float l = 0.f;
  for (int i = 0; i < nit; i++) {
    int j = li + i * 16;
    float p = __expf(e_reg[i] - m);
    l += p;
    p_lds[wv][j][head] = p;
    if (head == 0) s_lds[wv][j] = srcs[i];
  }
#pragma unroll
  for (int d = 1; d < 16; d <<= 1) l += __shfl_xor(l, d, 16);
  const float linv = 1.f / (l + 1e-16f);
  __builtin_amdgcn_s_waitcnt(0);
  float4 acc0 = make_float4(0.f, 0.f, 0.f, 0.f);
  float4 acc1 = make_float4(0.f, 0.f, 0.f, 0.f);
  int j = 0;
  for (; j + 1 <= n; j += 2) {
    float p0 = p_lds[wv][j][head];
    float p1 = p_lds[wv][j + 1][head];
    int s0 = s_lds[wv][j];
    int s1 = s_lds[wv][j + 1];
    float4 h0 = *(const float4*)&h[(size_t)s0 * 256 + c0];
    float4 h1 = *(const float4*)&h[(size_t)s1 * 256 + c0];
    acc0.x = fmaf(p0, h0.x, acc0.x); acc1.x = fmaf(p1, h1.x, acc1.x);
    acc0.y = fmaf(p0, h0.y, acc0.y); acc1.y = fmaf(p1, h1.y, acc1.y);
    acc0.z = fmaf(p0, h0.z, acc0.z); acc1.z = fmaf(p1, h1.z, acc1.z);
    acc0.w = fmaf(p0, h0.w, acc0.w); acc1.w = fmaf(p1, h1.w, acc1.w);
  }
  if (j <= n) {
    float p0 = p_lds[wv][j][head];
    int s0 = s_lds[wv][j];
    float4 h0 = *(const float4*)&h[(size_t)s0 * 256 + c0];
    acc0.x = fmaf(p0, h0.x, acc0.x);
    acc0.y = fmaf(p0, h0.y, acc0.y);
    acc0.z = fmaf(p0, h0.z, acc0.z);
    acc0.w = fmaf(p0, h0.w, acc0.w);
  }
  const float4 b4 = *(const float4*)&bias[c0];
  float4 o;
  o.x = fmaxf(fmaf(acc0.x + acc1.x, linv, b4.x), 0.f);
  o.y = fmaxf(fmaf(acc0.y + acc1.y, linv, b4.y), 0.f);
  o.z = fmaxf(fmaf(acc0.z + acc1.z, linv, b4.z), 0.f);
  o.w = fmaxf(fmaf(acc0.w + acc1.w, linv, b4.w), 0.f);
  *(float4*)&feat[(size_t)node * 256 + c0] = o;
}

// ---- BN stats ----
__global__ __launch_bounds__(256) void k_bn_partial(const float* __restrict__ feat,
                                                    double* __restrict__ psum,
                                                    double* __restrict__ psq) {
  const int c = threadIdx.x;
  const int r0 = blockIdx.x * 128;
  double s = 0.0, q = 0.0;
  for (int i = 0; i < 128; i++) {
    double v = (double)feat[(size_t)(r0 + i) * 256 + c];
    s += v;
    q += v * v;
  }
  psum[blockIdx.x * 256 + c] = s;
  psq[blockIdx.x * 256 + c] = q;
}

// cA/cB for output BN; sv[c]=cA*pwn, sv[256]=sum(cB*pwn) for the score
__global__ __launch_bounds__(1024) void k_bn_final(
    const double* __restrict__ psum, const double* __restrict__ psq,
    const float* __restrict__ gam, const float* __restrict__ bet,
    const float* __restrict__ pw, float* __restrict__ cA, float* __restrict__ cB,
    float* __restrict__ sv) {
  __shared__ double reds[4][256];
  __shared__ double redq[4][256];
  __shared__ double wsq[256];
  __shared__ double sb[256];
  const int t = threadIdx.x;
  const int c = t & 255, sl = t >> 8;
  double s = 0.0, q = 0.0;
  for (int i = sl * 64; i < sl * 64 + 64; i++) {
    s += psum[i * 256 + c];
    q += psq[i * 256 + c];
  }
  reds[sl][c] = s;
  redq[sl][c] = q;
  if (sl == 0) {
    double w = (double)pw[c];
    wsq[c] = w * w;
  }
  __syncthreads();
  if (t == 0) {
    double nn = 0.0;
    for (int i = 0; i < 256; i++) nn += wsq[i];
    wsq[0] = sqrt(nn);
  }
  __syncthreads();
  if (sl == 0) {
    s = reds[0][c] + reds[1][c] + reds[2][c] + reds[3][c];
    q = redq[0][c] + redq[1][c] + redq[2][c] + redq[3][c];
    double mean = s / (double)N_NODES;
    double var = q / (double)N_NODES - mean * mean;
    double a = (double)gam[c] / sqrt(var + 1e-5);
    double cb = (double)bet[c] - mean * a;
    cA[c] = (float)a;
    cB[c] = (float)cb;
    double pwnv = (double)pw[c] / wsq[0];
    sv[c] = (float)(a * pwnv);
    sb[c] = cb * pwnv;
  }
  __syncthreads();
  if (t == 0) {
    double s0 = 0.0;
    for (int i = 0; i < 256; i++) s0 += sb[i];
    sv[256] = (float)s0;
  }
}

// ---- score: one wave per node, coalesced ----
__global__ __launch_bounds__(256) void k_score(
    const float* __restrict__ feat, const float* __restrict__ sv,
    float* __restrict__ score) {
  const int lane = threadIdx.x & 63;
  const int node = blockIdx.x * 4 + (threadIdx.x >> 6);
  const int c0 = lane * 4;
  float4 f = *(const float4*)&feat[(size_t)node * 256 + c0];
  float4 w = *(const float4*)&sv[c0];
  float p = f.x * w.x + f.y * w.y + f.z * w.z + f.w * w.w;
#pragma unroll
  for (int d = 1; d < 64; d <<= 1) p += __shfl_xor(p, d, 64);
  if (lane == 0) score[node] = p + sv[256];
}

// ---- topk + gather: 8 blocks per graph, 64 nodes each ----
__global__ __launch_bounds__(256) void k_topk(
    const float* __restrict__ score, const float* __restrict__ feat,
    const float* __restrict__ cA, const float* __restrict__ cB,
    float* __restrict__ out) {
  __shared__ float ss[NPG];
  __shared__ int rnk[64];
  __shared__ float gt[64];
  const int g = blockIdx.x >> 3;
  const int part = blockIdx.x & 7;
  const int t = threadIdx.x;
  ss[t] = score[g * NPG + t];
  ss[t + 256] = score[g * NPG + t + 256];
  __syncthreads();
  const int ln = t & 3;
  const int ndl = part * 64 + (t >> 2);
  const float s = ss[ndl];
  int rank = 0;
  for (int j = ln * 128; j < ln * 128 + 128; j++) {
    float sj = ss[j];
    rank += (sj > s || (sj == s && j < ndl)) ? 1 : 0;
  }
  rank += __shfl_xor(rank, 1);
  rank += __shfl_xor(rank, 2);
  if (ln == 0) {
    rnk[t >> 2] = rank;
    gt[t >> 2] = tanhf(s);
  }
  __syncthreads();
  for (int idx = t; idx < 64 * 64; idx += 256) {
    int r = idx >> 6;
    int rank2 = rnk[r];
    if (rank2 < KKEEP) {
      int c4 = (idx & 63) * 4;
      int node = g * NPG + part * 64 + r;
      float4 f = *(const float4*)&feat[(size_t)node * 256 + c4];
      float4 a = *(const float4*)&cA[c4];
      float4 b = *(const float4*)&cB[c4];
      float tg = gt[r];
      float4 o;
      o.x = fmaf(f.x, a.x, b.x) * tg;
      o.y = fmaf(f.y, a.y, b.y) * tg;
      o.z = fmaf(f.z, a.z, b.z) * tg;
      o.w = fmaf(f.w, a.w, b.w) * tg;
      *(float4*)&out[(size_t)(g * KKEEP + rank2) * 256 + c4] = o;
    }
  }
}

extern "C" void kernel_launch(void* const* d_in, const int* in_sizes, int n_in,
                              void* d_out, int out_size, void* d_ws, size_t ws_size,
                              hipStream_t stream) {
  const float* x    = (const float*)d_in[0];
  const int*   ei   = (const int*)d_in[1];
  const float* W    = (const float*)d_in[2];
  const float* attS = (const float*)d_in[3];
  const float* attD = (const float*)d_in[4];
  const float* bias = (const float*)d_in[5];
  const float* gam  = (const float*)d_in[6];
  const float* bet  = (const float*)d_in[7];
  const float* pw   = (const float*)d_in[8];
  float* out = (float*)d_out;
  const int E = in_sizes[1] / 2;

  char* p = (char*)d_ws;
  float* h     = (float*)p; p += (size_t)N_NODES * 256 * 4;
  float* feat  = (float*)p; p += (size_t)N_NODES * 256 * 4;
  float* a_src = (float*)p; p += (size_t)N_NODES * 4 * 4;
  float* a_dst = (float*)p; p += (size_t)N_NODES * 4 * 4;
  float* score = (float*)p; p += (size_t)N_NODES * 4;
  double* psum = (double*)p; p += (size_t)256 * 256 * 8;
  double* psq  = (double*)p; p += (size_t)256 * 256 * 8;
  float* cA    = (float*)p; p += 256 * 4;
  float* cB    = (float*)p; p += 256 * 4;
  float* sv    = (float*)p; p += 260 * 4;
  unsigned short* wth  = (unsigned short*)p; p += (size_t)256 * 256 * 2;
  unsigned short* wtl  = (unsigned short*)p; p += (size_t)256 * 256 * 2;
  unsigned short* wtll = (unsigned short*)p; p += (size_t)256 * 256 * 2;
  int* cnt     = (int*)p;   p += (size_t)N_NODES * 4;
  unsigned short* nbr = (unsigned short*)p; p += (size_t)N_NODES * CAP * 2;

  hipMemsetAsync(cnt, 0, (size_t)N_NODES * 4, stream);
  k_hist_conv<<<2112, 256, 0, stream>>>(ei, E, cnt, nbr, W, wth, wtl, wtll);
  k_gemm<<<512, 256, 0, stream>>>(x, wth, wtl, wtll, attS, attD, h, a_src, a_dst);
  k_agg<<<N_NODES / 4, 256, 0, stream>>>(h, a_src, a_dst, cnt, nbr, bias, feat);
  k_bn_partial<<<256, 256, 0, stream>>>(feat, psum, psq);
  k_bn_final<<<1, 1024, 0, stream>>>(psum, psq, gam, bet, pw, cA, cB, sv);
  k_score<<<N_NODES / 4, 256, 0, stream>>>(feat, sv, score);
  k_topk<<<NGRAPH * 8, 256, 0, stream>>>(score, feat, cA, cB, out);
}